// Round 1
// baseline (880.240 us; speedup 1.0000x reference)
//
#include <hip/hip_runtime.h>
#include <math.h>

// Problem constants: B=8, N=128, D=512, H=16, DK=32
// Threshold is 2% of absmax(ref) -> bf16 MFMA for the two 131072x512x512 GEMMs.

using f32x4  = __attribute__((ext_vector_type(4))) float;
using bf16x8 = __attribute__((ext_vector_type(8))) short;

__device__ __forceinline__ unsigned short f2bf(float f) {
  union { float f; unsigned u; } v; v.f = f;
  unsigned u = v.u;
  u += 0x7FFFu + ((u >> 16) & 1u);      // round-to-nearest-even
  return (unsigned short)(u >> 16);
}
__device__ __forceinline__ float bf2f(unsigned short h) {
  union { unsigned u; float f; } v; v.u = ((unsigned)h) << 16; return v.f;
}

// ---------------------------------------------------------------------------
// Transpose-convert a 512x512 f32 weight matrix W[k][n] -> WT[n][k] bf16.
__global__ __launch_bounds__(256) void wt_kernel(const float* __restrict__ W,
                                                 unsigned short* __restrict__ WT) {
  __shared__ unsigned short T[64][72];
  int tile = blockIdx.x;                 // 64 tiles of 64x64
  int ti = tile >> 3, tj = tile & 7;
  int k0 = ti * 64, n0 = tj * 64;
  int t = threadIdx.x;
  int r = t >> 2, cq = (t & 3) * 16;
  const float* src = W + (size_t)(k0 + r) * 512 + n0 + cq;
#pragma unroll
  for (int j = 0; j < 16; ++j) T[r][cq + j] = f2bf(src[j]);
  __syncthreads();
  int c = t >> 2, rq = (t & 3) * 16;
  unsigned short* dst = WT + (size_t)(n0 + c) * 512 + k0 + rq;
#pragma unroll
  for (int j = 0; j < 16; ++j) dst[j] = T[rq + j][c];
}

// ---------------------------------------------------------------------------
// Adjacency softmax: adjsm[b,i,:] = softmax_j( mask[b,j] ? -lam*adj[b,i,j] : -inf )
__global__ __launch_bounds__(256) void adj_kernel(const float* __restrict__ adjm,
                                                  const int* __restrict__ mask,
                                                  const float* __restrict__ lam_p,
                                                  float* __restrict__ adjsm) {
  int row = blockIdx.x * 4 + (threadIdx.x >> 6);   // row < B*N = 1024
  int lane = threadIdx.x & 63;
  int b = row >> 7;
  float lam = lam_p[0];
  const float* src = adjm + (size_t)row * 128;
  int m0 = mask[b * 128 + lane], m1 = mask[b * 128 + 64 + lane];
  float x0 = m0 ? -lam * src[lane] : -INFINITY;
  float x1 = m1 ? -lam * src[64 + lane] : -INFINITY;
  float mx = fmaxf(x0, x1);
#pragma unroll
  for (int o = 32; o; o >>= 1) mx = fmaxf(mx, __shfl_xor(mx, o));
  float e0 = __expf(x0 - mx), e1 = __expf(x1 - mx);
  float s = e0 + e1;
#pragma unroll
  for (int o = 32; o; o >>= 1) s += __shfl_xor(s, o);
  float inv = 1.0f / s;
  adjsm[(size_t)row * 128 + lane] = e0 * inv;
  adjsm[(size_t)row * 128 + 64 + lane] = e1 * inv;
}

// ---------------------------------------------------------------------------
// GEMM: C[M x 512] = A[M x 512] @ W[512 x 512] + bias, via bf16 MFMA 16x16x32.
// WT is bf16 transposed weights WT[n][k].
// MODE 0: A f32 -> C f32.   MODE 1: A f32 -> C bf16.   MODE 2: A = Kbf16 * msg -> C f32.
// grid.x = (M/128)*4, bid>>2 = row block, bid&3 = col block (adjacent bids share A rows).
template <int MODE>
__global__ __launch_bounds__(256) void gemm_kernel(const void* __restrict__ Aptr,
                                                   const unsigned short* __restrict__ WT,
                                                   const float* __restrict__ bias,
                                                   void* __restrict__ Cptr,
                                                   const float* __restrict__ msg) {
  __shared__ unsigned short As[128 * 40];
  __shared__ unsigned short Bs[128 * 40];
  const int bid = blockIdx.x;
  const int rb = bid >> 2, cb = bid & 3;
  const int t = threadIdx.x;
  const int row0 = rb * 128, col0 = cb * 128;
  const int wave = t >> 6, lane = t & 63;
  const int wm = wave >> 1, wn = wave & 1;
  const int l15 = lane & 15, q4 = lane >> 4;
  const int arow = t >> 1, ahalf = t & 1;     // staging: 2 threads per row, 16 elems each

  f32x4 acc[4][4];
#pragma unroll
  for (int i = 0; i < 4; ++i)
#pragma unroll
    for (int j = 0; j < 4; ++j)
#pragma unroll
      for (int r = 0; r < 4; ++r) acc[i][j][r] = 0.0f;

  for (int ki = 0; ki < 16; ++ki) {
    const int k0 = ki * 32;
    // ---- stage A tile (128 x 32) into LDS as bf16
    if (MODE == 2) {
      const unsigned short* A = (const unsigned short*)Aptr;
      const int grow = row0 + arow;
      const unsigned short* src = A + (size_t)grow * 512 + k0 + ahalf * 16;
      uint4 p0 = *(const uint4*)src;
      uint4 p1 = *(const uint4*)(src + 8);
      // message scalar for this row and head h = ki (BK == DK == 32)
      int b = grow >> 14, m = (grow >> 7) & 127, n = grow & 127;
      float mv = msg[(((size_t)(b * 16 + ki) * 128 + m) * 128) + n];
      unsigned vals[8] = {p0.x, p0.y, p0.z, p0.w, p1.x, p1.y, p1.z, p1.w};
      union { unsigned short u[16]; uint4 q[2]; } w;
#pragma unroll
      for (int j = 0; j < 8; ++j) {
        w.u[2 * j]     = f2bf(bf2f((unsigned short)(vals[j] & 0xFFFFu)) * mv);
        w.u[2 * j + 1] = f2bf(bf2f((unsigned short)(vals[j] >> 16)) * mv);
      }
      unsigned short* d = &As[arow * 40 + ahalf * 16];
      *(uint4*)d = w.q[0];
      *(uint4*)(d + 8) = w.q[1];
    } else {
      const float* A = (const float*)Aptr;
      const float* src = A + (size_t)(row0 + arow) * 512 + k0 + ahalf * 16;
      f32x4 v0 = *(const f32x4*)(src + 0);
      f32x4 v1 = *(const f32x4*)(src + 4);
      f32x4 v2 = *(const f32x4*)(src + 8);
      f32x4 v3 = *(const f32x4*)(src + 12);
      union { unsigned short u[16]; uint4 q[2]; } w;
#pragma unroll
      for (int j = 0; j < 4; ++j) {
        w.u[j] = f2bf(v0[j]); w.u[4 + j] = f2bf(v1[j]);
        w.u[8 + j] = f2bf(v2[j]); w.u[12 + j] = f2bf(v3[j]);
      }
      unsigned short* d = &As[arow * 40 + ahalf * 16];
      *(uint4*)d = w.q[0];
      *(uint4*)(d + 8) = w.q[1];
    }
    // ---- stage B tile (WT rows col0..col0+127, k0..k0+31), already bf16
    {
      const unsigned short* src = WT + (size_t)(col0 + arow) * 512 + k0 + ahalf * 16;
      uint4 p0 = *(const uint4*)src;
      uint4 p1 = *(const uint4*)(src + 8);
      unsigned short* d = &Bs[arow * 40 + ahalf * 16];
      *(uint4*)d = p0;
      *(uint4*)(d + 8) = p1;
    }
    __syncthreads();
    // ---- MFMA
    bf16x8 af[4], bfr[4];
#pragma unroll
    for (int mt = 0; mt < 4; ++mt)
      af[mt] = *(const bf16x8*)&As[(wm * 64 + mt * 16 + l15) * 40 + q4 * 8];
#pragma unroll
    for (int nt = 0; nt < 4; ++nt)
      bfr[nt] = *(const bf16x8*)&Bs[(wn * 64 + nt * 16 + l15) * 40 + q4 * 8];
#pragma unroll
    for (int mt = 0; mt < 4; ++mt)
#pragma unroll
      for (int nt = 0; nt < 4; ++nt)
        acc[mt][nt] = __builtin_amdgcn_mfma_f32_16x16x32_bf16(af[mt], bfr[nt], acc[mt][nt], 0, 0, 0);
    __syncthreads();
  }
  // ---- epilogue: C[row][col] = acc + bias[col]
#pragma unroll
  for (int mt = 0; mt < 4; ++mt) {
#pragma unroll
    for (int nt = 0; nt < 4; ++nt) {
      int gcol = col0 + wn * 64 + nt * 16 + l15;
      float bv = bias[gcol];
#pragma unroll
      for (int r = 0; r < 4; ++r) {
        int grow = row0 + wm * 64 + mt * 16 + q4 * 4 + r;
        float val = acc[mt][nt][r] + bv;
        if (MODE == 1)
          ((unsigned short*)Cptr)[(size_t)grow * 512 + gcol] = f2bf(val);
        else
          ((float*)Cptr)[(size_t)grow * 512 + gcol] = val;
      }
    }
  }
}

// ---------------------------------------------------------------------------
// Scores: one block per (b,m). Computes for every n,h:
//   sout[b,h,m,n] = scale * q[b,m,h*32:]·K[b,m,n,h*32:]   (masked on n)
//   sinT[b,h,m,n] = scale * q[b,n,h*32:]·K[b,m,n,h*32:]   (= in_scores[b,h,n,m], masked on m)
__global__ __launch_bounds__(512) void scores_kernel(const unsigned short* __restrict__ Kbf,
                                                     const float* __restrict__ qw,
                                                     const int* __restrict__ mask,
                                                     float* __restrict__ sout,
                                                     float* __restrict__ sinT) {
  __shared__ float lso[16 * 9];
  __shared__ float lsi[16 * 9];
  const int bm = blockIdx.x;             // b*128 + m
  const int b = bm >> 7;
  const int t = threadIdx.x;
  const int wave = t >> 6, lane = t & 63;
  const float scale = 0.17677669529663687f;   // 1/sqrt(32)
  const int maskm = mask[bm];
  // q_m slice for this lane (8 consecutive f32)
  float qmr[8];
  {
    const float* qp = qw + (size_t)bm * 512 + lane * 8;
    f32x4 a = *(const f32x4*)qp, bq = *(const f32x4*)(qp + 4);
#pragma unroll
    for (int j = 0; j < 4; ++j) { qmr[j] = a[j]; qmr[4 + j] = bq[j]; }
  }
  for (int it = 0; it < 16; ++it) {
    int n = it * 8 + wave;
    const unsigned short* kp = Kbf + ((size_t)bm * 128 + n) * 512 + lane * 8;
    uint4 kv = *(const uint4*)kp;
    const float* qnp = qw + ((size_t)(b * 128 + n)) * 512 + lane * 8;
    f32x4 qa = *(const f32x4*)qnp, qb = *(const f32x4*)(qnp + 4);
    float qnr[8];
#pragma unroll
    for (int j = 0; j < 4; ++j) { qnr[j] = qa[j]; qnr[4 + j] = qb[j]; }
    unsigned vals[4] = {kv.x, kv.y, kv.z, kv.w};
    float so = 0.f, si = 0.f;
#pragma unroll
    for (int j = 0; j < 4; ++j) {
      float k0 = bf2f((unsigned short)(vals[j] & 0xFFFFu));
      float k1 = bf2f((unsigned short)(vals[j] >> 16));
      so += qmr[2 * j] * k0 + qmr[2 * j + 1] * k1;
      si += qnr[2 * j] * k0 + qnr[2 * j + 1] * k1;
    }
    so += __shfl_xor(so, 1); so += __shfl_xor(so, 2);
    si += __shfl_xor(si, 1); si += __shfl_xor(si, 2);
    int maskn = mask[b * 128 + n];
    if ((lane & 3) == 0) {
      int h = lane >> 2;
      lso[h * 9 + wave] = maskn ? so * scale : -INFINITY;
      lsi[h * 9 + wave] = maskm ? si * scale : -INFINITY;
    }
    __syncthreads();
    if (t < 256) {
      int sel = t >> 7, u = t & 127, h = u >> 3, w = u & 7;
      float v = sel ? lsi[h * 9 + w] : lso[h * 9 + w];
      float* dst = sel ? sinT : sout;
      dst[((size_t)(b * 16 + h) * 128 + (bm & 127)) * 128 + it * 8 + w] = v;
    }
    __syncthreads();
  }
}

// ---------------------------------------------------------------------------
// Batched 128x128 transpose: dst[mat][y][x] = src[mat][x][y]. 4 tiles of 64x64 per matrix.
__global__ __launch_bounds__(256) void tr128_kernel(const float* __restrict__ src,
                                                    float* __restrict__ dst) {
  __shared__ float T[64][65];
  int bid = blockIdx.x;
  int mat = bid >> 2, tile = bid & 3;
  int ti = tile >> 1, tj = tile & 1;
  const float* s = src + (size_t)mat * 16384;
  float* d = dst + (size_t)mat * 16384;
  int t = threadIdx.x;
  int r = t >> 2, cq = (t & 3) * 16;
#pragma unroll
  for (int j = 0; j < 16; ++j) T[r][cq + j] = s[(size_t)(ti * 64 + r) * 128 + tj * 64 + cq + j];
  __syncthreads();
  int c = t >> 2, rq = (t & 3) * 16;
#pragma unroll
  for (int j = 0; j < 16; ++j) d[(size_t)(tj * 64 + c) * 128 + ti * 64 + rq + j] = T[rq + j][c];
}

// ---------------------------------------------------------------------------
// In-place row softmax over rows of length 128 (rows = B*H*N).
__global__ __launch_bounds__(256) void rsm_kernel(float* __restrict__ x) {
  int row = blockIdx.x * 4 + (threadIdx.x >> 6);
  int lane = threadIdx.x & 63;
  float* p = x + (size_t)row * 128;
  float a0 = p[lane], a1 = p[lane + 64];
  float mx = fmaxf(a0, a1);
#pragma unroll
  for (int o = 32; o; o >>= 1) mx = fmaxf(mx, __shfl_xor(mx, o));
  float e0 = __expf(a0 - mx), e1 = __expf(a1 - mx);
  float s = e0 + e1;
#pragma unroll
  for (int o = 32; o; o >>= 1) s += __shfl_xor(s, o);
  float inv = 1.0f / s;
  p[lane] = e0 * inv;
  p[lane + 64] = e1 * inv;
}

// ---------------------------------------------------------------------------
// message = (out_attn + in_attn, diag -> in_attn) * adjsm ; written in place over in_attn.
__global__ __launch_bounds__(256) void msg_kernel(const float* __restrict__ outat,
                                                  float* __restrict__ inat_msg,
                                                  const float* __restrict__ adjsm) {
  size_t idx = (size_t)blockIdx.x * 256 + threadIdx.x;   // < B*H*N*N
  int c = (int)(idx & 127), r = (int)((idx >> 7) & 127);
  int bh = (int)(idx >> 14), b = bh >> 4;
  float o = outat[idx], in = inat_msg[idx];
  float mv = (r == c) ? in : (o + in);
  mv *= adjsm[((size_t)b * 128 + r) * 128 + c];
  inat_msg[idx] = mv;
}

// ---------------------------------------------------------------------------
// node_hidden: xpre[b, i, h*32+d] = sum_j msg[b,h,i,j] * v[b,j,h*32+d]
// grid = B*H*2 (64 rows per block).
__global__ __launch_bounds__(256) void node_kernel(const float* __restrict__ msg,
                                                   const float* __restrict__ vw,
                                                   float* __restrict__ xpre) {
  __shared__ float V[128 * 36];
  __shared__ float Mg[64 * 132];
  int bid = blockIdx.x;
  int bh = bid >> 1, half = bid & 1;
  int b = bh >> 4, h = bh & 15;
  int t = threadIdx.x;
#pragma unroll
  for (int i = 0; i < 16; ++i) {
    int idx = t + i * 256;                 // 4096 = 128*32
    int j = idx >> 5, dk = idx & 31;
    V[j * 36 + dk] = vw[((size_t)b * 128 + j) * 512 + h * 32 + dk];
  }
  const float* mrow = msg + (size_t)bh * 16384 + (size_t)half * 64 * 128;
#pragma unroll
  for (int i = 0; i < 32; ++i) {
    int idx = t + i * 256;                 // 8192 = 64*128
    int r = idx >> 7, c = idx & 127;
    Mg[r * 132 + c] = mrow[idx];
  }
  __syncthreads();
  int il = t >> 2, d0 = (t & 3) * 8;
  float acc[8] = {0, 0, 0, 0, 0, 0, 0, 0};
  for (int j = 0; j < 128; ++j) {
    float mv = Mg[il * 132 + j];
#pragma unroll
    for (int d = 0; d < 8; ++d) acc[d] += mv * V[j * 36 + d0 + d];
  }
  float* xp = xpre + ((size_t)b * 128 + half * 64 + il) * 512 + h * 32 + d0;
#pragma unroll
  for (int d = 0; d < 8; ++d) xp[d] = acc[d];
}

// ---------------------------------------------------------------------------
extern "C" void kernel_launch(void* const* d_in, const int* in_sizes, int n_in,
                              void* d_out, int out_size, void* d_ws, size_t ws_size,
                              hipStream_t stream) {
  const float* q_node   = (const float*)d_in[0];
  const float* v_node   = (const float*)d_in[1];
  const float* key_edge = (const float*)d_in[2];
  const float* adjm     = (const float*)d_in[3];
  const int*   mask     = (const int*)d_in[4];
  const float* Wq = (const float*)d_in[5];
  const float* bq = (const float*)d_in[6];
  const float* Wk = (const float*)d_in[7];
  const float* bk = (const float*)d_in[8];
  const float* Wv = (const float*)d_in[9];
  const float* bv = (const float*)d_in[10];
  const float* Wo = (const float*)d_in[11];
  const float* bo = (const float*)d_in[12];
  const float* We = (const float*)d_in[13];
  const float* be = (const float*)d_in[14];
  const float* lam = (const float*)d_in[15];

  char* ws = (char*)d_ws;
  unsigned short* Kbf   = (unsigned short*)(ws);                 // 134,217,728 B
  float* sout  = (float*)(ws + 134217728);                       //   8,388,608 B
  float* sinT  = (float*)(ws + 142606336);                       //   8,388,608 B
  float* msgb  = (float*)(ws + 150994944);                       //   8,388,608 B
  float* adjsm = (float*)(ws + 159383552);                       //     524,288 B
  float* qw    = (float*)(ws + 159907840);                       //   2,097,152 B
  float* vw    = (float*)(ws + 162004992);                       //   2,097,152 B
  float* xpre  = (float*)(ws + 164102144);                       //   2,097,152 B
  unsigned short* WqT = (unsigned short*)(ws + 166199296);       //   524,288 B each
  unsigned short* WkT = WqT + 262144;
  unsigned short* WvT = WkT + 262144;
  unsigned short* WoT = WvT + 262144;
  unsigned short* WeT = WoT + 262144;
  // total ws usage: 168,820,736 bytes

  float* out_x = (float*)d_out;          // (B,N,D)   = 524288 f32
  float* out_e = out_x + 524288;         // (B,N,N,D) = 67108864 f32

  wt_kernel<<<64, 256, 0, stream>>>(Wq, WqT);
  wt_kernel<<<64, 256, 0, stream>>>(Wk, WkT);
  wt_kernel<<<64, 256, 0, stream>>>(Wv, WvT);
  wt_kernel<<<64, 256, 0, stream>>>(Wo, WoT);
  wt_kernel<<<64, 256, 0, stream>>>(We, WeT);
  adj_kernel<<<256, 256, 0, stream>>>(adjm, mask, lam, adjsm);

  gemm_kernel<0><<<32, 256, 0, stream>>>(q_node, WqT, bq, qw, nullptr);
  gemm_kernel<0><<<32, 256, 0, stream>>>(v_node, WvT, bv, vw, nullptr);
  gemm_kernel<1><<<4096, 256, 0, stream>>>(key_edge, WkT, bk, Kbf, nullptr);

  scores_kernel<<<1024, 512, 0, stream>>>(Kbf, qw, mask, sout, sinT);
  tr128_kernel<<<512, 256, 0, stream>>>(sinT, msgb);
  rsm_kernel<<<4096, 256, 0, stream>>>(sout);
  rsm_kernel<<<4096, 256, 0, stream>>>(msgb);
  msg_kernel<<<8192, 256, 0, stream>>>(sout, msgb, adjsm);
  node_kernel<<<256, 256, 0, stream>>>(msgb, vw, xpre);

  gemm_kernel<0><<<32, 256, 0, stream>>>(xpre, WoT, bo, out_x, nullptr);
  gemm_kernel<2><<<4096, 256, 0, stream>>>(Kbf, WeT, be, out_e, msgb);
}

// Round 2
// 805.904 us; speedup vs baseline: 1.0922x; 1.0922x over previous
//
#include <hip/hip_runtime.h>
#include <math.h>

// Problem constants: B=8, N=128, D=512, H=16, DK=32
// Threshold is 2% of absmax(ref) -> bf16 MFMA for the two 131072x512x512 GEMMs.

using f32x4  = __attribute__((ext_vector_type(4))) float;
using bf16x8 = __attribute__((ext_vector_type(8))) short;

typedef const __attribute__((address_space(1))) unsigned int* gas_u32p;
typedef __attribute__((address_space(3))) unsigned int* las_u32p;

// async global->LDS, 16B per lane; LDS dest = wave-uniform base + lane*16
__device__ __forceinline__ void gll16(const void* gsrc, void* ldst) {
  __builtin_amdgcn_global_load_lds((gas_u32p)gsrc, (las_u32p)ldst, 16, 0, 0);
}

__device__ __forceinline__ unsigned short f2bf(float f) {
  union { float f; unsigned u; } v; v.f = f;
  unsigned u = v.u;
  u += 0x7FFFu + ((u >> 16) & 1u);      // round-to-nearest-even
  return (unsigned short)(u >> 16);
}
__device__ __forceinline__ float bf2f(unsigned short h) {
  union { unsigned u; float f; } v; v.u = ((unsigned)h) << 16; return v.f;
}
// pack two f32 -> dword of 2 bf16 (round-half-up via +0x8000, then v_perm)
__device__ __forceinline__ unsigned pack2(float lo, float hi) {
  union { float f; unsigned u; } a, b; a.f = lo; b.f = hi;
  return __builtin_amdgcn_perm(b.u + 0x8000u, a.u + 0x8000u, 0x07060302u);
}
// scale a dword of 2 bf16 by mv, repack
__device__ __forceinline__ unsigned scale_pair(unsigned u, float mv) {
  union { unsigned u; float f; } lo, hi;
  lo.u = u << 16; hi.u = u & 0xFFFF0000u;
  float a = lo.f * mv, b = hi.f * mv;
  return pack2(a, b);
}

// ---------------------------------------------------------------------------
// Transpose-convert a 512x512 f32 weight matrix W[k][n] -> WT[n][k] bf16.
__global__ __launch_bounds__(256) void wt_kernel(const float* __restrict__ W,
                                                 unsigned short* __restrict__ WT) {
  __shared__ unsigned short T[64][72];
  int tile = blockIdx.x;                 // 64 tiles of 64x64
  int ti = tile >> 3, tj = tile & 7;
  int k0 = ti * 64, n0 = tj * 64;
  int t = threadIdx.x;
  int r = t >> 2, cq = (t & 3) * 16;
  const float* src = W + (size_t)(k0 + r) * 512 + n0 + cq;
#pragma unroll
  for (int j = 0; j < 16; ++j) T[r][cq + j] = f2bf(src[j]);
  __syncthreads();
  int c = t >> 2, rq = (t & 3) * 16;
  unsigned short* dst = WT + (size_t)(n0 + c) * 512 + k0 + rq;
#pragma unroll
  for (int j = 0; j < 16; ++j) dst[j] = T[rq + j][c];
}

// ---------------------------------------------------------------------------
// Adjacency softmax: adjsm[b,i,:] = softmax_j( mask[b,j] ? -lam*adj[b,i,j] : -inf )
__global__ __launch_bounds__(256) void adj_kernel(const float* __restrict__ adjm,
                                                  const int* __restrict__ mask,
                                                  const float* __restrict__ lam_p,
                                                  float* __restrict__ adjsm) {
  int row = blockIdx.x * 4 + (threadIdx.x >> 6);   // row < B*N = 1024
  int lane = threadIdx.x & 63;
  int b = row >> 7;
  float lam = lam_p[0];
  const float* src = adjm + (size_t)row * 128;
  int m0 = mask[b * 128 + lane], m1 = mask[b * 128 + 64 + lane];
  float x0 = m0 ? -lam * src[lane] : -INFINITY;
  float x1 = m1 ? -lam * src[64 + lane] : -INFINITY;
  float mx = fmaxf(x0, x1);
#pragma unroll
  for (int o = 32; o; o >>= 1) mx = fmaxf(mx, __shfl_xor(mx, o));
  float e0 = __expf(x0 - mx), e1 = __expf(x1 - mx);
  float s = e0 + e1;
#pragma unroll
  for (int o = 32; o; o >>= 1) s += __shfl_xor(s, o);
  float inv = 1.0f / s;
  adjsm[(size_t)row * 128 + lane] = e0 * inv;
  adjsm[(size_t)row * 128 + 64 + lane] = e1 * inv;
}

// ---------------------------------------------------------------------------
// Small GEMM (v1 structure): C[M x 512] = A[M x 512] @ W + bias, f32 in/out.
// grid.x = (M/128)*4.
__global__ __launch_bounds__(256) void gemm_kernel(const float* __restrict__ A,
                                                   const unsigned short* __restrict__ WT,
                                                   const float* __restrict__ bias,
                                                   float* __restrict__ C) {
  __shared__ unsigned short As[128 * 40];
  __shared__ unsigned short Bs[128 * 40];
  const int bid = blockIdx.x;
  const int rb = bid >> 2, cb = bid & 3;
  const int t = threadIdx.x;
  const int row0 = rb * 128, col0 = cb * 128;
  const int wave = t >> 6, lane = t & 63;
  const int wm = wave >> 1, wn = wave & 1;
  const int l15 = lane & 15, q4 = lane >> 4;
  const int arow = t >> 1, ahalf = t & 1;

  f32x4 acc[4][4];
#pragma unroll
  for (int i = 0; i < 4; ++i)
#pragma unroll
    for (int j = 0; j < 4; ++j)
#pragma unroll
      for (int r = 0; r < 4; ++r) acc[i][j][r] = 0.0f;

  for (int ki = 0; ki < 16; ++ki) {
    const int k0 = ki * 32;
    {
      const float* src = A + (size_t)(row0 + arow) * 512 + k0 + ahalf * 16;
      f32x4 v0 = *(const f32x4*)(src + 0);
      f32x4 v1 = *(const f32x4*)(src + 4);
      f32x4 v2 = *(const f32x4*)(src + 8);
      f32x4 v3 = *(const f32x4*)(src + 12);
      union { unsigned short u[16]; uint4 q[2]; } w;
#pragma unroll
      for (int j = 0; j < 4; ++j) {
        w.u[j] = f2bf(v0[j]); w.u[4 + j] = f2bf(v1[j]);
        w.u[8 + j] = f2bf(v2[j]); w.u[12 + j] = f2bf(v3[j]);
      }
      unsigned short* d = &As[arow * 40 + ahalf * 16];
      *(uint4*)d = w.q[0];
      *(uint4*)(d + 8) = w.q[1];
    }
    {
      const unsigned short* src = WT + (size_t)(col0 + arow) * 512 + k0 + ahalf * 16;
      uint4 p0 = *(const uint4*)src;
      uint4 p1 = *(const uint4*)(src + 8);
      unsigned short* d = &Bs[arow * 40 + ahalf * 16];
      *(uint4*)d = p0;
      *(uint4*)(d + 8) = p1;
    }
    __syncthreads();
    bf16x8 af[4], bfr[4];
#pragma unroll
    for (int mt = 0; mt < 4; ++mt)
      af[mt] = *(const bf16x8*)&As[(wm * 64 + mt * 16 + l15) * 40 + q4 * 8];
#pragma unroll
    for (int nt = 0; nt < 4; ++nt)
      bfr[nt] = *(const bf16x8*)&Bs[(wn * 64 + nt * 16 + l15) * 40 + q4 * 8];
#pragma unroll
    for (int mt = 0; mt < 4; ++mt)
#pragma unroll
      for (int nt = 0; nt < 4; ++nt)
        acc[mt][nt] = __builtin_amdgcn_mfma_f32_16x16x32_bf16(af[mt], bfr[nt], acc[mt][nt], 0, 0, 0);
    __syncthreads();
  }
#pragma unroll
  for (int mt = 0; mt < 4; ++mt) {
#pragma unroll
    for (int nt = 0; nt < 4; ++nt) {
      int gcol = col0 + wn * 64 + nt * 16 + l15;
      float bv = bias[gcol];
#pragma unroll
      for (int r = 0; r < 4; ++r) {
        int grow = row0 + wm * 64 + mt * 16 + q4 * 4 + r;
        C[(size_t)grow * 512 + gcol] = acc[mt][nt][r] + bv;
      }
    }
  }
}

// ---------------------------------------------------------------------------
// Big GEMM v2 (m97-style): 128x256 tile, global_load_lds staging, XOR-swizzled
// LDS, fragment-time conversion. AMODE 1: A f32 -> C bf16 (K projection).
// AMODE 2: A bf16, scaled per (row, ki) by msg -> C f32 (edge output).
// grid.x = (M/128)*2; bid>>1 = row block, bid&1 = col block.
template <int AMODE>
__global__ __launch_bounds__(256, 2) void gemm2_kernel(
    const void* __restrict__ Aptr, const unsigned short* __restrict__ WT,
    const float* __restrict__ bias, void* __restrict__ Cptr,
    const float* __restrict__ msg) {
  constexpr int ABYTES = (AMODE == 2) ? 8192 : 16384;
  __shared__ char smem[ABYTES + 16384 + 512];
  float* Asf = (float*)smem;                       // AMODE!=2: 128x32 f32
  unsigned short* Abf = (unsigned short*)smem;     // AMODE==2: 128x32 bf16
  unsigned short* Bs = (unsigned short*)(smem + ABYTES);  // 256x32 bf16
  float* ms = (float*)(smem + ABYTES + 16384);     // AMODE==2: msg row (128)

  const int bid = blockIdx.x;
  const int rb = bid >> 1, cb = bid & 1;
  const int row0 = rb * 128, col0 = cb * 256;
  const int t = threadIdx.x;
  const int wave = t >> 6, lane = t & 63;
  const int wm = wave >> 1, wn = wave & 1;
  const int l15 = lane & 15, q4 = lane >> 4;

  size_t msbase = 0;
  if (AMODE == 2) {
    int b = row0 >> 14, m = (row0 >> 7) & 127;
    msbase = (size_t)(b * 16) * 16384 + m * 128;
  }

  f32x4 acc[4][8];
#pragma unroll
  for (int i = 0; i < 4; ++i)
#pragma unroll
    for (int j = 0; j < 8; ++j)
#pragma unroll
      for (int r = 0; r < 4; ++r) acc[i][j][r] = 0.0f;

  for (int ki = 0; ki < 16; ++ki) {
    const int k0 = ki * 32;
    // ---- stage A
    if (AMODE != 2) {
      const float* A = (const float*)Aptr;
#pragma unroll
      for (int c = 0; c < 4; ++c) {
        int ar = (wave * 4 + c) * 8 + (lane >> 3);
        int p = (lane & 7) >> 1, h = lane & 1;
        int gcol = ((p ^ (ar & 3)) << 3) + (h << 2);
        gll16(A + (size_t)(row0 + ar) * 512 + k0 + gcol,
              Asf + (size_t)(wave * 4 + c) * 256);
      }
    } else {
      const unsigned short* A = (const unsigned short*)Aptr;
#pragma unroll
      for (int c = 0; c < 2; ++c) {
        int ar = (wave * 2 + c) * 16 + (lane >> 2);
        int gq = (lane & 3) ^ (ar & 3);
        gll16(A + (size_t)(row0 + ar) * 512 + k0 + gq * 8,
              Abf + (size_t)(wave * 2 + c) * 512);
      }
      if (t < 128) ms[t] = msg[msbase + (size_t)ki * 16384 + t];
    }
    // ---- stage B (256 rows of WT)
#pragma unroll
    for (int c = 0; c < 4; ++c) {
      int br = (wave * 4 + c) * 16 + (lane >> 2);
      int gq = (lane & 3) ^ (br & 3);
      gll16(WT + (size_t)(col0 + br) * 512 + k0 + gq * 8,
            Bs + (size_t)(wave * 4 + c) * 512);
    }
    __syncthreads();

    // ---- fragments
    bf16x8 bfr[8], af[4];
#pragma unroll
    for (int nt = 0; nt < 8; ++nt) {
      int brow = wn * 128 + nt * 16 + l15;
      bfr[nt] = *(const bf16x8*)&Bs[brow * 32 + ((q4 ^ (brow & 3)) << 3)];
    }
    if (AMODE != 2) {
#pragma unroll
      for (int mt = 0; mt < 4; ++mt) {
        int arow = wm * 64 + mt * 16 + l15;
        const float* ap = &Asf[arow * 32 + ((q4 ^ (arow & 3)) << 3)];
        f32x4 v0 = *(const f32x4*)ap;
        f32x4 v1 = *(const f32x4*)(ap + 4);
        union { unsigned d[4]; bf16x8 v; } u;
        u.d[0] = pack2(v0[0], v0[1]); u.d[1] = pack2(v0[2], v0[3]);
        u.d[2] = pack2(v1[0], v1[1]); u.d[3] = pack2(v1[2], v1[3]);
        af[mt] = u.v;
      }
    } else {
#pragma unroll
      for (int mt = 0; mt < 4; ++mt) {
        int arow = wm * 64 + mt * 16 + l15;
        union { unsigned d[4]; bf16x8 v; } u;
        u.v = *(const bf16x8*)&Abf[arow * 32 + ((q4 ^ (arow & 3)) << 3)];
        float mv = ms[arow];
        u.d[0] = scale_pair(u.d[0], mv);
        u.d[1] = scale_pair(u.d[1], mv);
        u.d[2] = scale_pair(u.d[2], mv);
        u.d[3] = scale_pair(u.d[3], mv);
        af[mt] = u.v;
      }
    }
#pragma unroll
    for (int mt = 0; mt < 4; ++mt)
#pragma unroll
      for (int nt = 0; nt < 8; ++nt)
        acc[mt][nt] = __builtin_amdgcn_mfma_f32_16x16x32_bf16(af[mt], bfr[nt], acc[mt][nt], 0, 0, 0);
    __syncthreads();
  }
  // ---- epilogue
#pragma unroll
  for (int mt = 0; mt < 4; ++mt) {
#pragma unroll
    for (int nt = 0; nt < 8; ++nt) {
      int gcol = col0 + wn * 128 + nt * 16 + l15;
      float bv = bias[gcol];
#pragma unroll
      for (int r = 0; r < 4; ++r) {
        int grow = row0 + wm * 64 + mt * 16 + q4 * 4 + r;
        float val = acc[mt][nt][r] + bv;
        if (AMODE == 1)
          ((unsigned short*)Cptr)[(size_t)grow * 512 + gcol] = f2bf(val);
        else
          ((float*)Cptr)[(size_t)grow * 512 + gcol] = val;
      }
    }
  }
}

// ---------------------------------------------------------------------------
// Scores: one block per (b,m). Computes for every n,h:
//   sout[b,h,m,n] = scale * q[b,m,h*32:]·K[b,m,n,h*32:]   (masked on n)
//   sinT[b,h,m,n] = scale * q[b,n,h*32:]·K[b,m,n,h*32:]   (= in_scores[b,h,n,m], masked on m)
__global__ __launch_bounds__(512) void scores_kernel(const unsigned short* __restrict__ Kbf,
                                                     const float* __restrict__ qw,
                                                     const int* __restrict__ mask,
                                                     float* __restrict__ sout,
                                                     float* __restrict__ sinT) {
  __shared__ float lso[16 * 9];
  __shared__ float lsi[16 * 9];
  const int bm = blockIdx.x;             // b*128 + m
  const int b = bm >> 7;
  const int t = threadIdx.x;
  const int wave = t >> 6, lane = t & 63;
  const float scale = 0.17677669529663687f;   // 1/sqrt(32)
  const int maskm = mask[bm];
  float qmr[8];
  {
    const float* qp = qw + (size_t)bm * 512 + lane * 8;
    f32x4 a = *(const f32x4*)qp, bq = *(const f32x4*)(qp + 4);
#pragma unroll
    for (int j = 0; j < 4; ++j) { qmr[j] = a[j]; qmr[4 + j] = bq[j]; }
  }
  for (int it = 0; it < 16; ++it) {
    int n = it * 8 + wave;
    const unsigned short* kp = Kbf + ((size_t)bm * 128 + n) * 512 + lane * 8;
    uint4 kv = *(const uint4*)kp;
    const float* qnp = qw + ((size_t)(b * 128 + n)) * 512 + lane * 8;
    f32x4 qa = *(const f32x4*)qnp, qb = *(const f32x4*)(qnp + 4);
    float qnr[8];
#pragma unroll
    for (int j = 0; j < 4; ++j) { qnr[j] = qa[j]; qnr[4 + j] = qb[j]; }
    unsigned vals[4] = {kv.x, kv.y, kv.z, kv.w};
    float so = 0.f, si = 0.f;
#pragma unroll
    for (int j = 0; j < 4; ++j) {
      float k0 = bf2f((unsigned short)(vals[j] & 0xFFFFu));
      float k1 = bf2f((unsigned short)(vals[j] >> 16));
      so += qmr[2 * j] * k0 + qmr[2 * j + 1] * k1;
      si += qnr[2 * j] * k0 + qnr[2 * j + 1] * k1;
    }
    so += __shfl_xor(so, 1); so += __shfl_xor(so, 2);
    si += __shfl_xor(si, 1); si += __shfl_xor(si, 2);
    int maskn = mask[b * 128 + n];
    if ((lane & 3) == 0) {
      int h = lane >> 2;
      lso[h * 9 + wave] = maskn ? so * scale : -INFINITY;
      lsi[h * 9 + wave] = maskm ? si * scale : -INFINITY;
    }
    __syncthreads();
    if (t < 256) {
      int sel = t >> 7, u = t & 127, h = u >> 3, w = u & 7;
      float v = sel ? lsi[h * 9 + w] : lso[h * 9 + w];
      float* dst = sel ? sinT : sout;
      dst[((size_t)(b * 16 + h) * 128 + (bm & 127)) * 128 + it * 8 + w] = v;
    }
    __syncthreads();
  }
}

// ---------------------------------------------------------------------------
// Batched 128x128 transpose: dst[mat][y][x] = src[mat][x][y].
__global__ __launch_bounds__(256) void tr128_kernel(const float* __restrict__ src,
                                                    float* __restrict__ dst) {
  __shared__ float T[64][65];
  int bid = blockIdx.x;
  int mat = bid >> 2, tile = bid & 3;
  int ti = tile >> 1, tj = tile & 1;
  const float* s = src + (size_t)mat * 16384;
  float* d = dst + (size_t)mat * 16384;
  int t = threadIdx.x;
  int r = t >> 2, cq = (t & 3) * 16;
#pragma unroll
  for (int j = 0; j < 16; ++j) T[r][cq + j] = s[(size_t)(ti * 64 + r) * 128 + tj * 64 + cq + j];
  __syncthreads();
  int c = t >> 2, rq = (t & 3) * 16;
#pragma unroll
  for (int j = 0; j < 16; ++j) d[(size_t)(tj * 64 + c) * 128 + ti * 64 + rq + j] = T[rq + j][c];
}

// ---------------------------------------------------------------------------
// In-place row softmax over rows of length 128 (rows = B*H*N).
__global__ __launch_bounds__(256) void rsm_kernel(float* __restrict__ x) {
  int row = blockIdx.x * 4 + (threadIdx.x >> 6);
  int lane = threadIdx.x & 63;
  float* p = x + (size_t)row * 128;
  float a0 = p[lane], a1 = p[lane + 64];
  float mx = fmaxf(a0, a1);
#pragma unroll
  for (int o = 32; o; o >>= 1) mx = fmaxf(mx, __shfl_xor(mx, o));
  float e0 = __expf(a0 - mx), e1 = __expf(a1 - mx);
  float s = e0 + e1;
#pragma unroll
  for (int o = 32; o; o >>= 1) s += __shfl_xor(s, o);
  float inv = 1.0f / s;
  p[lane] = e0 * inv;
  p[lane + 64] = e1 * inv;
}

// ---------------------------------------------------------------------------
// message = (out_attn + in_attn, diag -> in_attn) * adjsm ; in place over in_attn.
__global__ __launch_bounds__(256) void msg_kernel(const float* __restrict__ outat,
                                                  float* __restrict__ inat_msg,
                                                  const float* __restrict__ adjsm) {
  size_t idx = (size_t)blockIdx.x * 256 + threadIdx.x;   // < B*H*N*N
  int c = (int)(idx & 127), r = (int)((idx >> 7) & 127);
  int bh = (int)(idx >> 14), b = bh >> 4;
  float o = outat[idx], in = inat_msg[idx];
  float mv = (r == c) ? in : (o + in);
  mv *= adjsm[((size_t)b * 128 + r) * 128 + c];
  inat_msg[idx] = mv;
}

// ---------------------------------------------------------------------------
// node_hidden: xpre[b, i, h*32+d] = sum_j msg[b,h,i,j] * v[b,j,h*32+d]
__global__ __launch_bounds__(256) void node_kernel(const float* __restrict__ msg,
                                                   const float* __restrict__ vw,
                                                   float* __restrict__ xpre) {
  __shared__ float V[128 * 36];
  __shared__ float Mg[64 * 132];
  int bid = blockIdx.x;
  int bh = bid >> 1, half = bid & 1;
  int b = bh >> 4, h = bh & 15;
  int t = threadIdx.x;
#pragma unroll
  for (int i = 0; i < 16; ++i) {
    int idx = t + i * 256;
    int j = idx >> 5, dk = idx & 31;
    V[j * 36 + dk] = vw[((size_t)b * 128 + j) * 512 + h * 32 + dk];
  }
  const float* mrow = msg + (size_t)bh * 16384 + (size_t)half * 64 * 128;
#pragma unroll
  for (int i = 0; i < 32; ++i) {
    int idx = t + i * 256;
    int r = idx >> 7, c = idx & 127;
    Mg[r * 132 + c] = mrow[idx];
  }
  __syncthreads();
  int il = t >> 2, d0 = (t & 3) * 8;
  float acc[8] = {0, 0, 0, 0, 0, 0, 0, 0};
  for (int j = 0; j < 128; ++j) {
    float mv = Mg[il * 132 + j];
#pragma unroll
    for (int d = 0; d < 8; ++d) acc[d] += mv * V[j * 36 + d0 + d];
  }
  float* xp = xpre + ((size_t)b * 128 + half * 64 + il) * 512 + h * 32 + d0;
#pragma unroll
  for (int d = 0; d < 8; ++d) xp[d] = acc[d];
}

// ---------------------------------------------------------------------------
extern "C" void kernel_launch(void* const* d_in, const int* in_sizes, int n_in,
                              void* d_out, int out_size, void* d_ws, size_t ws_size,
                              hipStream_t stream) {
  const float* q_node   = (const float*)d_in[0];
  const float* v_node   = (const float*)d_in[1];
  const float* key_edge = (const float*)d_in[2];
  const float* adjm     = (const float*)d_in[3];
  const int*   mask     = (const int*)d_in[4];
  const float* Wq = (const float*)d_in[5];
  const float* bq = (const float*)d_in[6];
  const float* Wk = (const float*)d_in[7];
  const float* bk = (const float*)d_in[8];
  const float* Wv = (const float*)d_in[9];
  const float* bv = (const float*)d_in[10];
  const float* Wo = (const float*)d_in[11];
  const float* bo = (const float*)d_in[12];
  const float* We = (const float*)d_in[13];
  const float* be = (const float*)d_in[14];
  const float* lam = (const float*)d_in[15];

  char* ws = (char*)d_ws;
  unsigned short* Kbf   = (unsigned short*)(ws);                 // 134,217,728 B
  float* sout  = (float*)(ws + 134217728);                       //   8,388,608 B
  float* sinT  = (float*)(ws + 142606336);                       //   8,388,608 B
  float* msgb  = (float*)(ws + 150994944);                       //   8,388,608 B
  float* adjsm = (float*)(ws + 159383552);                       //     524,288 B
  float* qw    = (float*)(ws + 159907840);                       //   2,097,152 B
  float* vw    = (float*)(ws + 162004992);                       //   2,097,152 B
  float* xpre  = (float*)(ws + 164102144);                       //   2,097,152 B
  unsigned short* WqT = (unsigned short*)(ws + 166199296);       //   524,288 B each
  unsigned short* WkT = WqT + 262144;
  unsigned short* WvT = WkT + 262144;
  unsigned short* WoT = WvT + 262144;
  unsigned short* WeT = WoT + 262144;
  // total ws usage: 168,820,736 bytes (same as round 1)

  float* out_x = (float*)d_out;          // (B,N,D)   = 524288 f32
  float* out_e = out_x + 524288;         // (B,N,N,D) = 67108864 f32

  wt_kernel<<<64, 256, 0, stream>>>(Wq, WqT);
  wt_kernel<<<64, 256, 0, stream>>>(Wk, WkT);
  wt_kernel<<<64, 256, 0, stream>>>(Wv, WvT);
  wt_kernel<<<64, 256, 0, stream>>>(Wo, WoT);
  wt_kernel<<<64, 256, 0, stream>>>(We, WeT);
  adj_kernel<<<256, 256, 0, stream>>>(adjm, mask, lam, adjsm);

  gemm_kernel<<<32, 256, 0, stream>>>(q_node, WqT, bq, qw);
  gemm_kernel<<<32, 256, 0, stream>>>(v_node, WvT, bv, vw);
  gemm2_kernel<1><<<2048, 256, 0, stream>>>(key_edge, WkT, bk, Kbf, nullptr);

  scores_kernel<<<1024, 512, 0, stream>>>(Kbf, qw, mask, sout, sinT);
  tr128_kernel<<<512, 256, 0, stream>>>(sinT, msgb);
  rsm_kernel<<<4096, 256, 0, stream>>>(sout);
  rsm_kernel<<<4096, 256, 0, stream>>>(msgb);
  msg_kernel<<<8192, 256, 0, stream>>>(sout, msgb, adjsm);
  node_kernel<<<256, 256, 0, stream>>>(msgb, vw, xpre);

  gemm_kernel<<<32, 256, 0, stream>>>(xpre, WoT, bo, out_x);
  gemm2_kernel<2><<<2048, 256, 0, stream>>>(Kbf, WeT, be, out_e, msgb);
}